// Round 8
// baseline (1710.415 us; speedup 1.0000x reference)
//
#include <hip/hip_runtime.h>
#include <hip/hip_bf16.h>

#define B_ 8
#define L_ 256
#define D_ 128
#define H_ 4
#define NB_ 2
#define ROWS (B_*L_)            // 2048
#define NEGV (-4294967295.0f)   // -(2^32)+1 as float
#define GRID 1024

typedef __hip_bfloat16 bf16;
typedef unsigned short us16;

__device__ __forceinline__ float us2f(us16 u){ return __uint_as_float(((unsigned)u)<<16); }
__device__ __forceinline__ us16 f2us(float f){ bf16 h=__float2bfloat16(f); return *(us16*)&h; }

struct KArgs {
    const int *log_seqs, *tmat, *pos_seqs, *neg_seqs;
    const float *item_emb, *posK, *posV, *timeK, *timeV;
    const float *ln1g, *ln1b, *bq, *bk, *bv, *ln2g, *ln2b, *b1, *b2, *lnfg, *lnfb;
    const float *Wq, *Wk, *Wv, *W1, *W2;
    float *seqs, *qin, *out;
    us16 *wsW, *tmK, *tmV, *Qb, *Kb, *Vb;
    int *bar;     // bar[0..31] group cnts, bar[32] root cnt, bar[33] generation
};

// grid barrier: two-level (32 groups of 32 blocks), sense-reversal via monotone gen.
// All 1024 blocks are co-resident by capacity (LDS 4x36864<=160K, 16 waves/CU,
// VGPR<=128 via launch_bounds) -> deadlock-free.
__device__ void gbar(int* bar){
    __syncthreads();               // compiler drains vmcnt before s_barrier
    if (threadIdx.x == 0){
        __threadfence();           // flush L2 (release)
        int grp = blockIdx.x & 31;
        int g = __hip_atomic_load(&bar[33], __ATOMIC_RELAXED, __HIP_MEMORY_SCOPE_AGENT);
        int a = __hip_atomic_fetch_add(&bar[grp], 1, __ATOMIC_ACQ_REL, __HIP_MEMORY_SCOPE_AGENT);
        if (a == 31){
            __hip_atomic_store(&bar[grp], 0, __ATOMIC_RELAXED, __HIP_MEMORY_SCOPE_AGENT);
            int r = __hip_atomic_fetch_add(&bar[32], 1, __ATOMIC_ACQ_REL, __HIP_MEMORY_SCOPE_AGENT);
            if (r == 31){
                __hip_atomic_store(&bar[32], 0, __ATOMIC_RELAXED, __HIP_MEMORY_SCOPE_AGENT);
                __hip_atomic_fetch_add(&bar[33], 1, __ATOMIC_RELEASE, __HIP_MEMORY_SCOPE_AGENT);
            } else {
                while (__hip_atomic_load(&bar[33], __ATOMIC_ACQUIRE, __HIP_MEMORY_SCOPE_AGENT) == g)
                    __builtin_amdgcn_s_sleep(1);
            }
        } else {
            while (__hip_atomic_load(&bar[33], __ATOMIC_ACQUIRE, __HIP_MEMORY_SCOPE_AGENT) == g)
                __builtin_amdgcn_s_sleep(1);
        }
    }
    __syncthreads();
    __threadfence();               // invalidate L1/L2 (acquire) for all waves
}

__device__ __forceinline__ void stage_w(const us16* __restrict__ Wg, us16* sW, int tid){
    const uint4* src = (const uint4*)Wg;
    uint4* dst = (uint4*)sW;
    #pragma unroll
    for (int j=0;j<8;j++) dst[j*256+tid] = src[j*256+tid];
}

// LayerNorm of 8 LDS rows (in-place safe: each thread rewrites only its own elems)
__device__ __forceinline__ void ln_rows(const float* sA, float* sOut,
        const float* __restrict__ g, const float* __restrict__ b,
        float* qin_out, int r0, int tid){
    int r = tid>>5, l = tid&31;
    const float* x = sA + r*128;
    float x0=x[l], x1=x[l+32], x2=x[l+64], x3=x[l+96];
    float s = x0+x1+x2+x3;
    #pragma unroll
    for (int o=16;o;o>>=1) s += __shfl_xor(s,o,64);
    float m = s*(1.f/128.f);
    float d0=x0-m,d1=x1-m,d2=x2-m,d3=x3-m;
    float v = d0*d0+d1*d1+d2*d2+d3*d3;
    #pragma unroll
    for (int o=16;o;o>>=1) v += __shfl_xor(v,o,64);
    float rstd = rsqrtf(v*(1.f/128.f)+1e-8f);
    float y0=d0*rstd*g[l]+b[l];
    float y1=d1*rstd*g[l+32]+b[l+32];
    float y2=d2*rstd*g[l+64]+b[l+64];
    float y3=d3*rstd*g[l+96]+b[l+96];
    float* o_ = sOut + r*128;
    o_[l]=y0; o_[l+32]=y1; o_[l+64]=y2; o_[l+96]=y3;
    if (qin_out){
        float* q = qin_out + (size_t)(r0+r)*128;
        q[l]=y0; q[l+32]=y1; q[l+64]=y2; q[l+96]=y3;
    }
}

__device__ __forceinline__ void gemm2x2(const float* A, const us16* sW,
        int ra, int rb, int c0, float* acc){
    float a00=0,a01=0,a10=0,a11=0;
    const float* Ar = A + ra*128;
    const float* Br = A + rb*128;
    #pragma unroll 8
    for (int k=0;k<128;k++){
        ushort2 wp = *(const ushort2*)(sW + k*128 + c0);
        float w0=us2f(wp.x), w1=us2f(wp.y);
        float x0=Ar[k], x1=Br[k];
        a00=fmaf(x0,w0,a00); a01=fmaf(x0,w1,a01);
        a10=fmaf(x1,w0,a10); a11=fmaf(x1,w1,a11);
    }
    acc[0]=a00; acc[1]=a01; acc[2]=a10; acc[3]=a11;
}

__device__ __forceinline__ void gemm1x2(const float* Ar, const us16* sW,
        int c0, float& o0, float& o1){
    float a0=0,a1=0;
    #pragma unroll 8
    for (int k=0;k<128;k++){
        ushort2 wp = *(const ushort2*)(sW + k*128 + c0);
        float x = Ar[k];
        a0 = fmaf(x, us2f(wp.x), a0);
        a1 = fmaf(x, us2f(wp.y), a1);
    }
    o0=a0; o1=a1;
}

__global__ __launch_bounds__(256, 4) void k_fused(KArgs a){
    __shared__ __align__(16) char smem[36864];
    int tid = threadIdx.x, bid = blockIdx.x;

    // ---------------- phase 0: prep (flat item split over all threads) ----------------
    {
        int gid = bid*256 + tid;
        if (gid < 65536){                        // embed: 65536 float4
            int r = gid >> 5, c4 = gid & 31;
            int id = a.log_seqs[r];
            float4 v = ((const float4*)a.item_emb)[id*32 + c4];
            float sc = (id==0)?0.f:11.3137085f;  // sqrt(128)
            v.x*=sc; v.y*=sc; v.z*=sc; v.w*=sc;
            ((float4*)a.seqs)[gid] = v;
        } else if (gid < 106496){                // weights: 10 x 4096 ushort4
            int j = gid - 65536;
            int m = j >> 12, idx = j & 4095;
            int mm = m % 5;
            const float* base = (mm==0)?a.Wq:(mm==1)?a.Wk:(mm==2)?a.Wv:(mm==3)?a.W1:a.W2;
            float4 v = ((const float4*)(base + (m/5)*16384))[idx];
            ushort4 o; o.x=f2us(v.x); o.y=f2us(v.y); o.z=f2us(v.z); o.w=f2us(v.w);
            ((ushort4*)(a.wsW + (size_t)m*16384))[idx] = o;
        } else if (gid < 106496+16448){          // time tables: 2 x 8224 float4
            int j = gid - 106496;
            if (j < 8224){
                float4 v = ((const float4*)a.timeK)[j];
                ushort4 o; o.x=f2us(v.x); o.y=f2us(v.y); o.z=f2us(v.z); o.w=f2us(v.w);
                ((ushort4*)a.tmK)[j] = o;
            } else {
                int j2 = j - 8224;
                float4 v = ((const float4*)a.timeV)[j2];
                ushort4 o; o.x=f2us(v.x); o.y=f2us(v.y); o.z=f2us(v.z); o.w=f2us(v.w);
                ((ushort4*)a.tmV)[j2] = o;
            }
        }
    }
    gbar(a.bar);

    for (int i=0;i<NB_;i++){
        // ---------------- qkv: blocks 0..767 = {Q,K,V} x 256 rowgroups ----------------
        if (bid < 768){
            us16* sW = (us16*)smem;
            float* sA = (float*)(smem+32768);
            int m = bid >> 8, rg = bid & 255, r0 = rg*8;
            ((float4*)sA)[tid] = ((const float4*)(a.seqs + (size_t)r0*128))[tid];
            stage_w(a.wsW + (size_t)(5*i+m)*16384, sW, tid);
            __syncthreads();
            if (m==0){
                ln_rows(sA, sA, a.ln1g+i*128, a.ln1b+i*128, a.qin, r0, tid);
                __syncthreads();
            }
            int cp=tid&63, rp=tid>>6, c0=2*cp, ra=2*rp, rb=ra+1;
            float acc[4];
            gemm2x2(sA, sW, ra, rb, c0, acc);
            if (m==0){
                const float* bb = a.bq + i*128;
                float b0v=bb[c0], b1v=bb[c0+1];
                ushort2 s0; s0.x=f2us(acc[0]+b0v); s0.y=f2us(acc[1]+b1v);
                ushort2 s1; s1.x=f2us(acc[2]+b0v); s1.y=f2us(acc[3]+b1v);
                *(ushort2*)(a.Qb + (size_t)(r0+ra)*128 + c0) = s0;
                *(ushort2*)(a.Qb + (size_t)(r0+rb)*128 + c0) = s1;
            } else {
                const float* bb = (m==1)? a.bk+i*128 : a.bv+i*128;
                const float* pp = (m==1)? a.posK : a.posV;
                us16* Oo = (m==1)? a.Kb : a.Vb;
                int qa = (r0+ra)&(L_-1), qb2 = (r0+rb)&(L_-1);
                float b0v=bb[c0], b1v=bb[c0+1];
                ushort2 s0; s0.x=f2us(acc[0]+b0v+pp[qa*128+c0]);  s0.y=f2us(acc[1]+b1v+pp[qa*128+c0+1]);
                ushort2 s1; s1.x=f2us(acc[2]+b0v+pp[qb2*128+c0]); s1.y=f2us(acc[3]+b1v+pp[qb2*128+c0+1]);
                *(ushort2*)(Oo + (size_t)(r0+ra)*128 + c0) = s0;
                *(ushort2*)(Oo + (size_t)(r0+rb)*128 + c0) = s1;
            }
        }
        gbar(a.bar);

        // ---------------- attn: all 1024 blocks, one per (b, q-pair) ----------------
        {
            float* sQ  = (float*)smem;                 // [2][128]
            float* sS  = (float*)(smem+1024);          // [2][4][256]
            int*   sTM = (int*)(smem+9216);            // [2][256]
            float* sPr = (float*)(smem+11264);         // [2][8][128]
            float* sRed  = (float*)(smem+19456);       // [2][2]
            float* sRed2 = (float*)(smem+19472);       // [2][2]
            int b = bid >> 7, p = bid & 127;
            int q1 = p, q2 = L_-1-p;
            int b0 = b*L_;
            int r1 = b0+q1, r2 = b0+q2;
            bool pad1 = a.log_seqs[r1]==0, pad2 = a.log_seqs[r2]==0;
            const float scale = 0.17677669529663687f;  // 1/sqrt(32)
            if (tid < 128) sQ[tid]       = us2f(a.Qb[(size_t)r1*128+tid])*scale;
            else           sQ[128+tid-128+0] = us2f(a.Qb[(size_t)r2*128+(tid-128)])*scale;
            int k = tid;
            int tmv1 = a.tmat[(size_t)r1*L_+k], tmv2 = a.tmat[(size_t)r2*L_+k];
            sTM[k] = tmv1; sTM[256+k] = tmv2;
            __syncthreads();

            // phase 1: scores = Qs.(K' + timeK[tm])
            {
                const uint4* K4 = (const uint4*)(a.Kb + (size_t)(b0+k)*128);
                #pragma unroll
                for (int ii=0;ii<2;ii++){
                    int qq = ii? q2:q1; bool pad = ii? pad2:pad1;
                    int tm = ii? tmv2:tmv1;
                    bool act = (k<=qq) && !pad;
                    float acc[4] = {0.f,0.f,0.f,0.f};
                    if (act){
                        const uint4* T4 = (const uint4*)(a.tmK + (size_t)tm*128);
                        const float4* Q4 = (const float4*)(sQ + ii*128);
                        #pragma unroll
                        for (int c=0;c<16;c++){
                            uint4 kv = K4[c];
                            uint4 tv = T4[c];
                            float4 qa = Q4[2*c], qb = Q4[2*c+1];
                            const us16* ku = (const us16*)&kv;
                            const us16* tu = (const us16*)&tv;
                            acc[c>>2] += qa.x*(us2f(ku[0])+us2f(tu[0]))
                                       + qa.y*(us2f(ku[1])+us2f(tu[1]))
                                       + qa.z*(us2f(ku[2])+us2f(tu[2]))
                                       + qa.w*(us2f(ku[3])+us2f(tu[3]))
                                       + qb.x*(us2f(ku[4])+us2f(tu[4]))
                                       + qb.y*(us2f(ku[5])+us2f(tu[5]))
                                       + qb.z*(us2f(ku[6])+us2f(tu[6]))
                                       + qb.w*(us2f(ku[7])+us2f(tu[7]));
                        }
                    }
                    #pragma unroll
                    for (int h=0;h<H_;h++) sS[(ii*4+h)*256+k] = act ? acc[h] : NEGV;
                }
            }
            __syncthreads();

            // phase 2: softmax; wave h -> head h, both queries
            {
                int h = tid>>6, lane = tid&63;
                #pragma unroll
                for (int ii=0;ii<2;ii++){
                    float* row = sS + (ii*4+h)*256;
                    float v0=row[lane], v1=row[lane+64], v2=row[lane+128], v3=row[lane+192];
                    float m = fmaxf(fmaxf(v0,v1),fmaxf(v2,v3));
                    #pragma unroll
                    for (int o=32;o;o>>=1) m = fmaxf(m,__shfl_xor(m,o,64));
                    float e0=__expf(v0-m), e1=__expf(v1-m), e2=__expf(v2-m), e3=__expf(v3-m);
                    float ss=e0+e1+e2+e3;
                    #pragma unroll
                    for (int o=32;o;o>>=1) ss += __shfl_xor(ss,o,64);
                    float inv = 1.f/ss;
                    row[lane]=e0*inv; row[lane+64]=e1*inv; row[lane+128]=e2*inv; row[lane+192]=e3*inv;
                }
            }
            __syncthreads();

            // phase 3: A @ (V' + timeV[tm]); causal clamp
            {
                int dq = tid&31, slice = tid>>5, h = dq>>3;
                #pragma unroll
                for (int ii=0;ii<2;ii++){
                    int qq = ii? q2:q1; bool pad = ii? pad2:pad1;
                    int kend = pad? L_ : qq+1;
                    int k0 = slice*32;
                    int kmax = kend - k0; kmax = kmax<0?0:(kmax>32?32:kmax);
                    const float* row = sS + (ii*4+h)*256;
                    float a0=0,a1=0,a2=0,a3=0;
                    for (int kk=0;kk<kmax;kk++){
                        int kx = k0+kk;
                        float aa = row[kx];
                        int tmk = sTM[ii*256+kx];
                        ushort4 v4 = ((const ushort4*)(a.Vb + (size_t)(b0+kx)*128))[dq];
                        ushort4 t4 = ((const ushort4*)(a.tmV + (size_t)tmk*128))[dq];
                        a0 = fmaf(aa, us2f(v4.x)+us2f(t4.x), a0);
                        a1 = fmaf(aa, us2f(v4.y)+us2f(t4.y), a1);
                        a2 = fmaf(aa, us2f(v4.z)+us2f(t4.z), a2);
                        a3 = fmaf(aa, us2f(v4.w)+us2f(t4.w), a3);
                    }
                    ((float4*)(sPr + (ii*8+slice)*128))[dq] = make_float4(a0,a1,a2,a3);
                }
            }
            __syncthreads();

            // epilogue: +q_in residual, LN2, write seqs
            {
                int ii = tid>>7, l = tid&127;
                int rr = ii? r2:r1;
                float v = a.qin[(size_t)rr*128 + l];
                #pragma unroll
                for (int sl=0;sl<8;sl++) v += sPr[(ii*8+sl)*128 + l];
                float s = v;
                #pragma unroll
                for (int o=32;o;o>>=1) s += __shfl_xor(s,o,64);
                if ((tid&63)==0) sRed[ii*2 + ((tid>>6)&1)] = s;
                __syncthreads();
                float m = (sRed[ii*2]+sRed[ii*2+1])*(1.f/128.f);
                float d = v-m;
                float vv = d*d;
                #pragma unroll
                for (int o=32;o;o>>=1) vv += __shfl_xor(vv,o,64);
                if ((tid&63)==0) sRed2[ii*2 + ((tid>>6)&1)] = vv;
                __syncthreads();
                float rstd = rsqrtf((sRed2[ii*2]+sRed2[ii*2+1])*(1.f/128.f)+1e-8f);
                a.seqs[(size_t)rr*128+l] = d*rstd*a.ln2g[i*128+l]+a.ln2b[i*128+l];
            }
        }
        gbar(a.bar);

        // ---------------- ffn: blocks 0..511, 4 rows each, in place ----------------
        if (bid < 512){
            us16* sW = (us16*)smem;
            float* sA = (float*)(smem+32768);
            float* sH = (float*)(smem+34816);
            int r0 = bid*4;
            sA[tid]     = a.seqs[(size_t)r0*128 + tid];
            sA[tid+256] = a.seqs[(size_t)r0*128 + tid + 256];
            stage_w(a.wsW + (size_t)(5*i+3)*16384, sW, tid);
            __syncthreads();
            int rp=tid>>6, l=tid&63, c0=2*l;
            const float* b1b = a.b1 + i*128;
            const float* b2b = a.b2 + i*128;
            float h0,h1;
            gemm1x2(sA + rp*128, sW, c0, h0, h1);
            sH[rp*128+c0]   = fmaxf(h0+b1b[c0],0.f);
            sH[rp*128+c0+1] = fmaxf(h1+b1b[c0+1],0.f);
            __syncthreads();
            stage_w(a.wsW + (size_t)(5*i+4)*16384, sW, tid);
            __syncthreads();
            float f0,f1;
            gemm1x2(sH + rp*128, sW, c0, f0, f1);
            bool msk = a.log_seqs[r0+rp]==0;
            f0 = msk?0.f:(f0+b2b[c0]  +sA[rp*128+c0]);
            f1 = msk?0.f:(f1+b2b[c0+1]+sA[rp*128+c0+1]);
            a.seqs[(size_t)(r0+rp)*128 + c0]   = f0;
            a.seqs[(size_t)(r0+rp)*128 + c0+1] = f1;
        }
        gbar(a.bar);
    }

    // ---------------- final LN + logits: blocks 0..255, 8 rows each ----------------
    if (bid < 256){
        float* sA = (float*)smem;
        float* sH = (float*)(smem+4096);
        int r0 = bid*8;
        ((float4*)sA)[tid] = ((const float4*)(a.seqs + (size_t)r0*128))[tid];
        __syncthreads();
        ln_rows(sA, sH, a.lnfg, a.lnfb, nullptr, r0, tid);
        __syncthreads();
        int w = tid>>6, lane = tid&63;
        #pragma unroll
        for (int j=0;j<4;j++){
            int o = w*4 + j;                 // 16 = 8 rows x {pos,neg}
            int row = o>>1; int neg = o&1;
            int rg = r0 + row;
            int id = neg ? a.neg_seqs[rg] : a.pos_seqs[rg];
            const float* e = a.item_emb + (size_t)id*128;
            const float* fr = sH + row*128;
            float s = fr[lane]*e[lane] + fr[lane+64]*e[lane+64];
            #pragma unroll
            for (int oo=32;oo;oo>>=1) s += __shfl_xor(s,oo,64);
            if (lane==0) a.out[(neg?ROWS:0) + rg] = s;
        }
    }
}

extern "C" void kernel_launch(void* const* d_in, const int* in_sizes, int n_in,
                              void* d_out, int out_size, void* d_ws, size_t ws_size,
                              hipStream_t stream) {
    KArgs a;
    a.log_seqs = (const int*)d_in[1];
    a.tmat     = (const int*)d_in[2];
    a.pos_seqs = (const int*)d_in[3];
    a.neg_seqs = (const int*)d_in[4];
    a.item_emb = (const float*)d_in[5];
    a.posK  = (const float*)d_in[6];
    a.posV  = (const float*)d_in[7];
    a.timeK = (const float*)d_in[8];
    a.timeV = (const float*)d_in[9];
    a.ln1g = (const float*)d_in[10];
    a.ln1b = (const float*)d_in[11];
    a.Wq = (const float*)d_in[12];
    a.bq = (const float*)d_in[13];
    a.Wk = (const float*)d_in[14];
    a.bk = (const float*)d_in[15];
    a.Wv = (const float*)d_in[16];
    a.bv = (const float*)d_in[17];
    a.ln2g = (const float*)d_in[18];
    a.ln2b = (const float*)d_in[19];
    a.W1 = (const float*)d_in[20];
    a.b1 = (const float*)d_in[21];
    a.W2 = (const float*)d_in[22];
    a.b2 = (const float*)d_in[23];
    a.lnfg = (const float*)d_in[24];
    a.lnfb = (const float*)d_in[25];

    const size_t MB = 1u<<20;
    char* wsb = (char*)d_ws;
    a.seqs = (float*)(wsb + 0);            // 1MB
    a.qin  = (float*)(wsb + 1*MB);         // 1MB
    a.Qb   = (us16*) (wsb + 2*MB);         // 0.5MB
    a.Kb   = (us16*) (wsb + 2*MB + 512*1024);
    a.Vb   = (us16*) (wsb + 3*MB);
    a.wsW  = (us16*) (wsb + 4*MB);         // 320KB
    a.tmK  = (us16*) (wsb + 5*MB);         // 65792B
    a.tmV  = (us16*) (wsb + 5*MB + 128*1024);
    a.bar  = (int*)  (wsb + 6*MB);         // 34 ints
    a.out  = (float*)d_out;

    hipMemsetAsync(a.bar, 0, 256, stream); // zero barrier state (graph-capturable)
    k_fused<<<GRID, 256, 0, stream>>>(a);
}

// Round 9
// 212.815 us; speedup vs baseline: 8.0371x; 8.0371x over previous
//
#include <hip/hip_runtime.h>
#include <hip/hip_bf16.h>

#define L_ 256
#define H_ 4
#define ROWS 2048
#define NEGV (-4294967295.0f)   // -(2^32)+1 as float

typedef unsigned short us16;

__device__ __forceinline__ float us2f(us16 u){ return __uint_as_float(((unsigned)u)<<16); }
__device__ __forceinline__ us16 f2us(float f){ __hip_bfloat16 h=__float2bfloat16(f); return *(us16*)&h; }

struct KArgs {
    const int *log_seqs, *tmat, *pos_seqs, *neg_seqs;
    const float *item_emb, *posK, *posV, *timeK, *timeV;
    const float *ln1g, *ln1b, *bq, *bk, *bv, *ln2g, *ln2b, *b1, *b2, *lnfg, *lnfb;
    const float *Wq, *Wk, *Wv, *W1, *W2;
    float *qin0, *qin1, *out;
    us16 *wsW, *tmK, *tmV, *Qb0, *Kb0, *Vb0, *Qb1, *Kb1, *Vb1;
};

// stage 128x128 bf16 matrix (32KB) from workspace into LDS: 8 uint4/thread
__device__ __forceinline__ void stage_w(const us16* __restrict__ Wg, us16* sW, int tid){
    const uint4* src=(const uint4*)Wg;
    uint4* dst=(uint4*)sW;
    #pragma unroll
    for(int j=0;j<8;j++) dst[j*256+tid]=src[j*256+tid];
}

// LayerNorm of 8 LDS rows in place; thread t: row t>>5, 4 elems strided 32.
__device__ __forceinline__ void ln_rows(float* sA,
        const float* __restrict__ g, const float* __restrict__ b,
        float* qin_out, int r0, int tid){
    int r=tid>>5, l=tid&31;
    float* x=sA+r*128;
    float x0=x[l],x1=x[l+32],x2=x[l+64],x3=x[l+96];
    float s=x0+x1+x2+x3;
    #pragma unroll
    for(int o=16;o;o>>=1) s+=__shfl_xor(s,o,64);
    float m=s*(1.f/128.f);
    float d0=x0-m,d1=x1-m,d2=x2-m,d3=x3-m;
    float v=d0*d0+d1*d1+d2*d2+d3*d3;
    #pragma unroll
    for(int o=16;o;o>>=1) v+=__shfl_xor(v,o,64);
    float rstd=rsqrtf(v*(1.f/128.f)+1e-8f);
    float y0=d0*rstd*g[l]+b[l];
    float y1=d1*rstd*g[l+32]+b[l+32];
    float y2=d2*rstd*g[l+64]+b[l+64];
    float y3=d3*rstd*g[l+96]+b[l+96];
    x[l]=y0; x[l+32]=y1; x[l+64]=y2; x[l+96]=y3;
    if(qin_out){
        float* q=qin_out+(size_t)(r0+r)*128;
        q[l]=y0; q[l+32]=y1; q[l+64]=y2; q[l+96]=y3;
    }
}

// 2-row x 2-col register tile over K=128 from LDS
__device__ __forceinline__ void gemm2x2(const float* A, const us16* sW,
        int ra, int rb, int c0, float* acc){
    float a00=0,a01=0,a10=0,a11=0;
    const float* Ar=A+ra*128;
    const float* Br=A+rb*128;
    #pragma unroll 8
    for(int k=0;k<128;k++){
        ushort2 wp=*(const ushort2*)(sW+k*128+c0);
        float w0=us2f(wp.x), w1=us2f(wp.y);
        float x0=Ar[k], x1=Br[k];
        a00=fmaf(x0,w0,a00); a01=fmaf(x0,w1,a01);
        a10=fmaf(x1,w0,a10); a11=fmaf(x1,w1,a11);
    }
    acc[0]=a00; acc[1]=a01; acc[2]=a10; acc[3]=a11;
}

// k_pre: bid<768: embed+LN1+QKV(L0), 8 rows/block, weights converted during stage.
//        bid 768..879: convert 7 weight mats fp32->bf16 into wsW.
//        bid 880..945: convert timeK/timeV tables to bf16.
__global__ __launch_bounds__(256) void k_pre(KArgs a){
    __shared__ __align__(16) char smem[36864];
    int tid=threadIdx.x, bid=blockIdx.x;
    if(bid<768){
        us16* sW=(us16*)smem;
        float* sA=(float*)(smem+32768);
        int m=bid>>8, rg=bid&255, r0=rg*8;
        {   // embed 8 rows: thread -> (row tid>>5, float4 chunk tid&31)
            int rl=tid>>5, c4=tid&31;
            int id=a.log_seqs[r0+rl];
            float4 v=((const float4*)a.item_emb)[id*32+c4];
            float sc = id? 11.3137085f : 0.f;   // sqrt(128), pad-zeroed
            v.x*=sc; v.y*=sc; v.z*=sc; v.w*=sc;
            ((float4*)sA)[tid]=v;
        }
        const float* Wsrc=(m==0)?a.Wq:(m==1)?a.Wk:a.Wv;
        {   // stage fp32 weights -> bf16 LDS
            const float4* src=(const float4*)Wsrc;
            ushort4* dst=(ushort4*)sW;
            #pragma unroll
            for(int j=0;j<16;j++){
                float4 w=src[j*256+tid];
                ushort4 o; o.x=f2us(w.x);o.y=f2us(w.y);o.z=f2us(w.z);o.w=f2us(w.w);
                dst[j*256+tid]=o;
            }
        }
        __syncthreads();
        if(m==0){ ln_rows(sA, a.ln1g, a.ln1b, a.qin0, r0, tid); __syncthreads(); }
        int cp=tid&63, rp=tid>>6, c0=2*cp, ra=2*rp, rb=ra+1;
        float acc[4];
        gemm2x2(sA,sW,ra,rb,c0,acc);
        if(m==0){
            float b0v=a.bq[c0], b1v=a.bq[c0+1];
            ushort2 s0; s0.x=f2us(acc[0]+b0v); s0.y=f2us(acc[1]+b1v);
            ushort2 s1; s1.x=f2us(acc[2]+b0v); s1.y=f2us(acc[3]+b1v);
            *(ushort2*)(a.Qb0+(size_t)(r0+ra)*128+c0)=s0;
            *(ushort2*)(a.Qb0+(size_t)(r0+rb)*128+c0)=s1;
        } else {
            const float* bb=(m==1)?a.bk:a.bv;
            const float* pp=(m==1)?a.posK:a.posV;
            us16* Oo=(m==1)?a.Kb0:a.Vb0;
            int qa=(r0+ra)&255, qb2=(r0+rb)&255;
            float b0v=bb[c0], b1v=bb[c0+1];
            ushort2 s0; s0.x=f2us(acc[0]+b0v+pp[qa*128+c0]);  s0.y=f2us(acc[1]+b1v+pp[qa*128+c0+1]);
            ushort2 s1; s1.x=f2us(acc[2]+b0v+pp[qb2*128+c0]); s1.y=f2us(acc[3]+b1v+pp[qb2*128+c0+1]);
            *(ushort2*)(Oo+(size_t)(r0+ra)*128+c0)=s0;
            *(ushort2*)(Oo+(size_t)(r0+rb)*128+c0)=s1;
        }
    } else if(bid<880){
        int j=bid-768; int m=j>>4; int idx=(j&15)*256+tid;
        const float* base;
        switch(m){
            case 0: base=a.W1; break;        case 1: base=a.W2; break;
            case 2: base=a.Wq+16384; break;  case 3: base=a.Wk+16384; break;
            case 4: base=a.Wv+16384; break;  case 5: base=a.W1+16384; break;
            default: base=a.W2+16384; break;
        }
        float4 v=((const float4*)base)[idx];
        ushort4 o; o.x=f2us(v.x);o.y=f2us(v.y);o.z=f2us(v.z);o.w=f2us(v.w);
        ((ushort4*)(a.wsW+(size_t)m*16384))[idx]=o;
    } else {
        int gi=(bid-880)*256+tid;     // 2 x 8224 float4
        if(gi<8224){
            float4 v=((const float4*)a.timeK)[gi];
            ushort4 o; o.x=f2us(v.x);o.y=f2us(v.y);o.z=f2us(v.z);o.w=f2us(v.w);
            ((ushort4*)a.tmK)[gi]=o;
        } else if(gi<16448){
            int g2=gi-8224;
            float4 v=((const float4*)a.timeV)[g2];
            ushort4 o; o.x=f2us(v.x);o.y=f2us(v.y);o.z=f2us(v.z);o.w=f2us(v.w);
            ((ushort4*)a.tmV)[g2]=o;
        }
    }
}

// k_blk: one block per (b, q-pair {p,255-p}).
// attention -> LN2 -> FFN -> mask, then (layer0) LN1+QKV of layer1, (layer1) LNf+logits.
__global__ __launch_bounds__(256,4) void k_blk(KArgs a, int layer){
    __shared__ __align__(16) char smem[36864];
    float* sQ  =(float*)smem;            // [2][128]   (phase A)
    float* sS  =(float*)(smem+1024);     // [2][4][256]
    int*   sTM =(int*)  (smem+9216);     // [2][256]
    float* sPr =(float*)(smem+11264);    // [2][8][128]
    float* sRed=(float*)(smem+19456);    // 4
    float* sRed2=(float*)(smem+19472);   // 4
    us16*  sW  =(us16*) smem;            // [16384]    (phase B, overlays A)
    float* sX  =(float*)(smem+32768);    // [2][128]
    float* sH  =(float*)(smem+33792);    // [2][128]
    float* sY  =(float*)(smem+34816);    // [2][128]
    float* sRB =(float*)(smem+35840);    // 8

    int tid=threadIdx.x, bid=blockIdx.x;
    int b=bid>>7, p=bid&127;
    int q1=p, q2=255-p, b0=b*L_;
    int r1=b0+q1, r2=b0+q2;
    bool pad1=a.log_seqs[r1]==0, pad2=a.log_seqs[r2]==0;
    const us16* Qb = layer? a.Qb1:a.Qb0;
    const us16* Kb = layer? a.Kb1:a.Kb0;
    const us16* Vb = layer? a.Vb1:a.Vb0;
    const float* qin = layer? a.qin1:a.qin0;
    const float scale=0.17677669529663687f;   // 1/sqrt(32)
    if(tid<128) sQ[tid]=us2f(Qb[(size_t)r1*128+tid])*scale;
    else        sQ[tid]=us2f(Qb[(size_t)r2*128+(tid-128)])*scale;
    int k=tid;
    int tm1=a.tmat[(size_t)r1*L_+k], tm2=a.tmat[(size_t)r2*L_+k];
    sTM[k]=tm1; sTM[256+k]=tm2;
    __syncthreads();

    // phase 1: scores = Qs.(K' + timeK[tm]); K row shared between queries
    {
        const uint4* K4=(const uint4*)(Kb+(size_t)(b0+k)*128);
        #pragma unroll
        for(int i2=0;i2<2;i2++){
            int qq=i2?q2:q1; bool pad=i2?pad2:pad1;
            int tm=i2?tm2:tm1;
            bool act=(k<=qq)&&!pad;
            float acc[4]={0.f,0.f,0.f,0.f};
            if(act){
                const uint4* T4=(const uint4*)(a.tmK+(size_t)tm*128);
                const float4* Q4=(const float4*)(sQ+i2*128);
                #pragma unroll
                for(int c=0;c<16;c++){
                    uint4 kv=K4[c]; uint4 tv=T4[c];
                    float4 qa=Q4[2*c], qb=Q4[2*c+1];
                    const us16* ku=(const us16*)&kv;
                    const us16* tu=(const us16*)&tv;
                    acc[c>>2]+= qa.x*(us2f(ku[0])+us2f(tu[0]))
                              + qa.y*(us2f(ku[1])+us2f(tu[1]))
                              + qa.z*(us2f(ku[2])+us2f(tu[2]))
                              + qa.w*(us2f(ku[3])+us2f(tu[3]))
                              + qb.x*(us2f(ku[4])+us2f(tu[4]))
                              + qb.y*(us2f(ku[5])+us2f(tu[5]))
                              + qb.z*(us2f(ku[6])+us2f(tu[6]))
                              + qb.w*(us2f(ku[7])+us2f(tu[7]));
                }
            }
            #pragma unroll
            for(int h=0;h<H_;h++) sS[(i2*4+h)*256+k]= act? acc[h]:NEGV;
        }
    }
    __syncthreads();

    // phase 2: softmax; wave h -> head h, both queries
    {
        int h=tid>>6, lane=tid&63;
        #pragma unroll
        for(int i2=0;i2<2;i2++){
            float* row=sS+(i2*4+h)*256;
            float v0=row[lane],v1=row[lane+64],v2=row[lane+128],v3=row[lane+192];
            float mm=fmaxf(fmaxf(v0,v1),fmaxf(v2,v3));
            #pragma unroll
            for(int o=32;o;o>>=1) mm=fmaxf(mm,__shfl_xor(mm,o,64));
            float e0=__expf(v0-mm),e1=__expf(v1-mm),e2=__expf(v2-mm),e3=__expf(v3-mm);
            float ss=e0+e1+e2+e3;
            #pragma unroll
            for(int o=32;o;o>>=1) ss+=__shfl_xor(ss,o,64);
            float inv=1.f/ss;
            row[lane]=e0*inv; row[lane+64]=e1*inv; row[lane+128]=e2*inv; row[lane+192]=e3*inv;
        }
    }
    __syncthreads();

    // phase 3: A @ (V'+timeV[tm]); queries split across thread halves, 16B loads
    {
        int i2=tid>>7, s8=(tid>>4)&7, dq=tid&15;    // 8 dims per thread, head=dq>>2
        int qq=i2?q2:q1; bool pad=i2?pad2:pad1;
        int kend=pad?L_:qq+1;
        int k0=s8*32;
        int kmax=kend-k0; kmax=kmax<0?0:(kmax>32?32:kmax);
        const float* row=sS+(i2*4+(dq>>2))*256;
        const int* tmrow=sTM+i2*256;
        float a0=0,a1=0,a2=0,a3=0,a4=0,a5=0,a6=0,a7=0;
        for(int kk=0;kk<kmax;kk++){
            int kx=k0+kk;
            float aa=row[kx];
            int tmk=tmrow[kx];
            uint4 v4=((const uint4*)(Vb+(size_t)(b0+kx)*128))[dq];
            uint4 t4=((const uint4*)(a.tmV+(size_t)tmk*128))[dq];
            const us16* vu=(const us16*)&v4;
            const us16* tu=(const us16*)&t4;
            a0=fmaf(aa,us2f(vu[0])+us2f(tu[0]),a0);
            a1=fmaf(aa,us2f(vu[1])+us2f(tu[1]),a1);
            a2=fmaf(aa,us2f(vu[2])+us2f(tu[2]),a2);
            a3=fmaf(aa,us2f(vu[3])+us2f(tu[3]),a3);
            a4=fmaf(aa,us2f(vu[4])+us2f(tu[4]),a4);
            a5=fmaf(aa,us2f(vu[5])+us2f(tu[5]),a5);
            a6=fmaf(aa,us2f(vu[6])+us2f(tu[6]),a6);
            a7=fmaf(aa,us2f(vu[7])+us2f(tu[7]),a7);
        }
        float* dst=sPr+(i2*8+s8)*128+dq*8;
        ((float4*)dst)[0]=make_float4(a0,a1,a2,a3);
        ((float4*)dst)[1]=make_float4(a4,a5,a6,a7);
    }
    __syncthreads();

    // epilogue: +qin residual, LN2 -> sX
    int ii=tid>>7, l=tid&127;
    bool padown = ii? pad2:pad1;
    int rr = ii? r2:r1;
    int qown = ii? q2:q1;
    {
        float v=qin[(size_t)rr*128+l];
        #pragma unroll
        for(int sl=0;sl<8;sl++) v+=sPr[(ii*8+sl)*128+l];
        float s=v;
        #pragma unroll
        for(int o=32;o;o>>=1) s+=__shfl_xor(s,o,64);
        if((tid&63)==0) sRed[ii*2+((tid>>6)&1)]=s;
        __syncthreads();
        float m=(sRed[ii*2]+sRed[ii*2+1])*(1.f/128.f);
        float d=v-m;
        float vv=d*d;
        #pragma unroll
        for(int o=32;o;o>>=1) vv+=__shfl_xor(vv,o,64);
        if((tid&63)==0) sRed2[ii*2+((tid>>6)&1)]=vv;
        __syncthreads();
        float rstd=rsqrtf((sRed2[ii*2]+sRed2[ii*2+1])*(1.f/128.f)+1e-8f);
        float y=d*rstd*a.ln2g[layer*128+l]+a.ln2b[layer*128+l];
        __syncthreads();                    // sPr/sRed reads done
        sX[ii*128+l]=y;
    }
    __syncthreads();

    // FFN: h = relu(sX@W1+b1); f = h@W2+b2 + sX; mask
    int cc=l;
    stage_w(a.wsW+(size_t)(layer?5:0)*16384, sW, tid);
    __syncthreads();
    {
        const float* xr=sX+ii*128;
        float h=0;
        #pragma unroll 16
        for(int k2=0;k2<128;k2++) h=fmaf(xr[k2],us2f(sW[k2*128+cc]),h);
        h=fmaxf(h+a.b1[layer*128+cc],0.f);
        __syncthreads();                    // W1 reads done
        sH[ii*128+cc]=h;
    }
    __syncthreads();
    stage_w(a.wsW+(size_t)(layer?6:1)*16384, sW, tid);
    __syncthreads();
    float f;
    {
        const float* hr=sH+ii*128;
        float acc=0;
        #pragma unroll 16
        for(int k2=0;k2<128;k2++) acc=fmaf(hr[k2],us2f(sW[k2*128+cc]),acc);
        f=acc+a.b2[layer*128+cc]+sX[ii*128+cc];
        if(padown) f=0.f;
    }
    __syncthreads();                        // all sX/sW reads done

    if(layer==0){
        // LN1(layer1) on f -> sX (gemm input for Q) ; raw f -> sY (input for K,V)
        sY[ii*128+cc]=f;
        float s=f;
        #pragma unroll
        for(int o=32;o;o>>=1) s+=__shfl_xor(s,o,64);
        if((tid&63)==0) sRB[ii*2+((tid>>6)&1)]=s;
        __syncthreads();
        float m=(sRB[ii*2]+sRB[ii*2+1])*(1.f/128.f);
        float d=f-m;
        float vv=d*d;
        #pragma unroll
        for(int o=32;o;o>>=1) vv+=__shfl_xor(vv,o,64);
        if((tid&63)==0) sRB[4+ii*2+((tid>>6)&1)]=vv;
        __syncthreads();
        float rstd=rsqrtf((sRB[4+ii*2]+sRB[5+ii*2])*(1.f/128.f)+1e-8f);
        float y1=d*rstd*a.ln1g[128+cc]+a.ln1b[128+cc];
        a.qin1[(size_t)rr*128+cc]=y1;
        sX[ii*128+cc]=y1;
        __syncthreads();
        // Q(L1)
        stage_w(a.wsW+(size_t)2*16384, sW, tid);
        __syncthreads();
        {
            const float* xr=sX+ii*128;
            float acc=0;
            #pragma unroll 16
            for(int k2=0;k2<128;k2++) acc=fmaf(xr[k2],us2f(sW[k2*128+cc]),acc);
            acc+=a.bq[128+cc];
            a.Qb1[(size_t)rr*128+cc]=f2us(acc);
        }
        __syncthreads();
        // K(L1)
        stage_w(a.wsW+(size_t)3*16384, sW, tid);
        __syncthreads();
        {
            const float* yr=sY+ii*128;
            float acc=0;
            #pragma unroll 16
            for(int k2=0;k2<128;k2++) acc=fmaf(yr[k2],us2f(sW[k2*128+cc]),acc);
            acc+=a.bk[128+cc]+a.posK[qown*128+cc];
            a.Kb1[(size_t)rr*128+cc]=f2us(acc);
        }
        __syncthreads();
        // V(L1)
        stage_w(a.wsW+(size_t)4*16384, sW, tid);
        __syncthreads();
        {
            const float* yr=sY+ii*128;
            float acc=0;
            #pragma unroll 16
            for(int k2=0;k2<128;k2++) acc=fmaf(yr[k2],us2f(sW[k2*128+cc]),acc);
            acc+=a.bv[128+cc]+a.posV[qown*128+cc];
            a.Vb1[(size_t)rr*128+cc]=f2us(acc);
        }
    } else {
        // LNf + logits
        float s=f;
        #pragma unroll
        for(int o=32;o;o>>=1) s+=__shfl_xor(s,o,64);
        if((tid&63)==0) sRB[ii*2+((tid>>6)&1)]=s;
        __syncthreads();
        float m=(sRB[ii*2]+sRB[ii*2+1])*(1.f/128.f);
        float d=f-m;
        float vv=d*d;
        #pragma unroll
        for(int o=32;o;o>>=1) vv+=__shfl_xor(vv,o,64);
        if((tid&63)==0) sRB[4+ii*2+((tid>>6)&1)]=vv;
        __syncthreads();
        float rstd=rsqrtf((sRB[4+ii*2]+sRB[5+ii*2])*(1.f/128.f)+1e-8f);
        sX[ii*128+cc]=d*rstd*a.lnfg[cc]+a.lnfb[cc];
        __syncthreads();
        int w=tid>>6, lane=tid&63;
        int rowi=w>>1, neg=w&1;
        int rg = rowi? r2:r1;
        int id = neg? a.neg_seqs[rg] : a.pos_seqs[rg];
        const float* e=a.item_emb+(size_t)id*128;
        float s2 = sX[rowi*128+lane]*e[lane] + sX[rowi*128+lane+64]*e[lane+64];
        #pragma unroll
        for(int o=32;o;o>>=1) s2+=__shfl_xor(s2,o,64);
        if(lane==0) a.out[neg*ROWS+rg]=s2;
    }
}

extern "C" void kernel_launch(void* const* d_in, const int* in_sizes, int n_in,
                              void* d_out, int out_size, void* d_ws, size_t ws_size,
                              hipStream_t stream) {
    KArgs a;
    a.log_seqs=(const int*)d_in[1];
    a.tmat    =(const int*)d_in[2];
    a.pos_seqs=(const int*)d_in[3];
    a.neg_seqs=(const int*)d_in[4];
    a.item_emb=(const float*)d_in[5];
    a.posK =(const float*)d_in[6];
    a.posV =(const float*)d_in[7];
    a.timeK=(const float*)d_in[8];
    a.timeV=(const float*)d_in[9];
    a.ln1g=(const float*)d_in[10];
    a.ln1b=(const float*)d_in[11];
    a.Wq=(const float*)d_in[12];
    a.bq=(const float*)d_in[13];
    a.Wk=(const float*)d_in[14];
    a.bk=(const float*)d_in[15];
    a.Wv=(const float*)d_in[16];
    a.bv=(const float*)d_in[17];
    a.ln2g=(const float*)d_in[18];
    a.ln2b=(const float*)d_in[19];
    a.W1=(const float*)d_in[20];
    a.b1=(const float*)d_in[21];
    a.W2=(const float*)d_in[22];
    a.b2=(const float*)d_in[23];
    a.lnfg=(const float*)d_in[24];
    a.lnfb=(const float*)d_in[25];

    const size_t MB=1u<<20;
    char* w=(char*)d_ws;
    a.qin0=(float*)(w+0*MB);
    a.qin1=(float*)(w+1*MB);
    a.Qb0 =(us16*) (w+2*MB);
    a.Kb0 =(us16*) (w+2*MB+512*1024);
    a.Vb0 =(us16*) (w+3*MB);
    a.Qb1 =(us16*) (w+3*MB+512*1024);
    a.Kb1 =(us16*) (w+4*MB);
    a.Vb1 =(us16*) (w+4*MB+512*1024);
    a.wsW =(us16*) (w+5*MB);              // 7 x 32KB
    a.tmK =(us16*) (w+5*MB+256*1024);     // 65792 B
    a.tmV =(us16*) (w+5*MB+384*1024);
    a.out =(float*)d_out;

    k_pre<<<946,256,0,stream>>>(a);
    k_blk<<<1024,256,0,stream>>>(a,0);
    k_blk<<<1024,256,0,stream>>>(a,1);
}